// Round 4
// baseline (1516.932 us; speedup 1.0000x reference)
//
#include <hip/hip_runtime.h>

// HeteroGraphSage: 2-layer SAGEConv(mean) + PReLU + input-skip.
// N=100000, IN=D=64, E=1600000, fp32.
// CSR build (hist/scan/fill -> dst-sorted packed edges), then per-layer fused
// kernel: edge-parallel gather via plain atomicAdd into LDS tile (ds_add_f32,
// stride 65 = conflict-free), then dense (lane=node, wave-uniform weight rows
// -> scalar loads). R4: removed misaligned int4 load (UB) and unsafeAtomicAdd
// on shared (flat-atomic-to-LDS risk) — both replaced with canonical forms.

#define BLOCK 512

__global__ __launch_bounds__(256) void hist_kernel(
    const int* __restrict__ dst, int* __restrict__ deg, int E)
{
    int i = blockIdx.x * blockDim.x + threadIdx.x;
    int stride = gridDim.x * blockDim.x;
    for (int e = i; e < E; e += stride) atomicAdd(&deg[dst[e]], 1);
}

__global__ __launch_bounds__(256) void bsum_kernel(
    const int* __restrict__ deg, int* __restrict__ bsum, int n)
{
    __shared__ int sh[256];
    int i = blockIdx.x * 256 + threadIdx.x;
    sh[threadIdx.x] = (i < n) ? deg[i] : 0;
    __syncthreads();
    for (int s = 128; s > 0; s >>= 1) {
        if (threadIdx.x < s) sh[threadIdx.x] += sh[threadIdx.x + s];
        __syncthreads();
    }
    if (threadIdx.x == 0) bsum[blockIdx.x] = sh[0];
}

__global__ __launch_bounds__(512) void scanb_kernel(
    const int* __restrict__ bsum, int* __restrict__ bsumX, int nb)
{
    __shared__ int sh[512];
    int tid = threadIdx.x;
    int v = (tid < nb) ? bsum[tid] : 0;
    sh[tid] = v;
    __syncthreads();
    for (int off = 1; off < 512; off <<= 1) {
        int t = (tid >= off) ? sh[tid - off] : 0;
        __syncthreads();
        sh[tid] += t;
        __syncthreads();
    }
    bsumX[tid] = sh[tid] - v;   // exclusive
}

// writes rowStart AND seeds cursor with the same value
__global__ __launch_bounds__(256) void rowstart_kernel(
    const int* __restrict__ deg, const int* __restrict__ bsumX,
    int* __restrict__ rowStart, int* __restrict__ cursor, int n)
{
    __shared__ int sh[256];
    int tid = threadIdx.x;
    int i = blockIdx.x * 256 + tid;
    int v = (i < n) ? deg[i] : 0;
    sh[tid] = v;
    __syncthreads();
    for (int off = 1; off < 256; off <<= 1) {
        int t = (tid >= off) ? sh[tid - off] : 0;
        __syncthreads();
        sh[tid] += t;
        __syncthreads();
    }
    if (i < n) {
        int rs = sh[tid] - v + bsumX[blockIdx.x];
        rowStart[i] = rs;
        cursor[i]   = rs;
    }
}

// esort[pos] = src | (dstLocal << 26)  (src < 2^26; dstLocal = dst & 63)
__global__ __launch_bounds__(256) void fill_kernel(
    const int* __restrict__ src, const int* __restrict__ dst,
    int* __restrict__ cursor, unsigned int* __restrict__ esort, int E)
{
    int i = blockIdx.x * blockDim.x + threadIdx.x;
    int stride = gridDim.x * blockDim.x;
    for (int e = i; e < E; e += stride) {
        int d = dst[e];
        int pos = atomicAdd(&cursor[d], 1);
        esort[pos] = (unsigned int)src[e] | ((unsigned int)(d & 63) << 26);
    }
}

// out = PReLU( mean_agg @ wl^T + bl + hin @ wr^T , a ) + x0 @ wskip^T + bskip
__global__ __launch_bounds__(BLOCK) void layer_kernel(
    const int* __restrict__ rowStart, const int* __restrict__ deg,
    const unsigned int* __restrict__ esort,
    const float* __restrict__ hin, const float* __restrict__ x0,
    const float* __restrict__ wl, const float* __restrict__ bl,
    const float* __restrict__ wr, const float* __restrict__ wskip,
    const float* __restrict__ bskip, const float* __restrict__ aprelu,
    float* __restrict__ out, int n, int E)
{
    // stride 65: bank = (65*r + c)%32 = (r + c)%32 -> worst 2-way (free)
    // for both the per-edge atomic (fixed r, lane=c) and the per-node read
    // (lane=r, fixed c) patterns.
    __shared__ float agg_s[64 * 65];
    __shared__ float h_s[64 * 65];
    __shared__ float x_s[64 * 65];

    const int tid  = threadIdx.x;
    const int lane = tid & 63;
    const int wvu  = __builtin_amdgcn_readfirstlane(tid >> 6);  // 0..7

    const int tileBase = blockIdx.x * 64;
    const int tileEnd  = min(tileBase + 64, n);

    for (int i = tid; i < 64 * 65; i += BLOCK) agg_s[i] = 0.f;
    for (int i = tid; i < 64 * 64; i += BLOCK) {
        const int nl = i >> 6, d = i & 63;
        const int node = tileBase + nl;
        float hv = 0.f, xv = 0.f;
        if (node < n) {
            hv = hin[(size_t)node * 64 + d];
            xv = x0[(size_t)node * 64 + d];
        }
        h_s[nl * 65 + d] = hv;
        x_s[nl * 65 + d] = xv;
    }
    __syncthreads();

    // ---- Phase A: edge-parallel gather. 8 waves x 4 edges/iter.
    // Scalar (wave-uniform, 4B-aligned) esort loads; ds_add_f32 accumulation.
    const int eBeg = __builtin_amdgcn_readfirstlane(rowStart[tileBase]);
    const int eEnd = __builtin_amdgcn_readfirstlane(
        (tileEnd < n) ? rowStart[tileEnd] : E);

    for (int eb = eBeg + wvu * 4; eb < eEnd; eb += 32) {
        if (eb + 4 <= eEnd) {
            const unsigned int p0 = esort[eb + 0];
            const unsigned int p1 = esort[eb + 1];
            const unsigned int p2 = esort[eb + 2];
            const unsigned int p3 = esort[eb + 3];
            const float v0 = hin[(size_t)(p0 & 0x03FFFFFFu) * 64 + lane];
            const float v1 = hin[(size_t)(p1 & 0x03FFFFFFu) * 64 + lane];
            const float v2 = hin[(size_t)(p2 & 0x03FFFFFFu) * 64 + lane];
            const float v3 = hin[(size_t)(p3 & 0x03FFFFFFu) * 64 + lane];
            atomicAdd(&agg_s[(p0 >> 26) * 65 + lane], v0);
            atomicAdd(&agg_s[(p1 >> 26) * 65 + lane], v1);
            atomicAdd(&agg_s[(p2 >> 26) * 65 + lane], v2);
            atomicAdd(&agg_s[(p3 >> 26) * 65 + lane], v3);
        } else {
            for (int e = eb; e < eEnd; e++) {
                const unsigned int p = esort[e];
                const float v = hin[(size_t)(p & 0x03FFFFFFu) * 64 + lane];
                atomicAdd(&agg_s[(p >> 26) * 65 + lane], v);
            }
        }
    }
    __syncthreads();

    // ---- Phase B: dense. lane = node; this wave covers dims [wvu*8, wvu*8+8).
    const int node = tileBase + lane;
    const float dgf = (node < n) ? (float)deg[node] : 1.f;
    const float inv = 1.0f / fmaxf(dgf, 1.0f);

    float acc1[8], acc2[8], acc3[8];
#pragma unroll
    for (int dd = 0; dd < 8; dd++) { acc1[dd] = 0.f; acc2[dd] = 0.f; acc3[dd] = 0.f; }

    for (int kc = 0; kc < 8; kc++) {
        float ak[8], hk[8], xk[8];
#pragma unroll
        for (int k = 0; k < 8; k++) {
            ak[k] = agg_s[lane * 65 + kc * 8 + k];
            hk[k] = h_s[lane * 65 + kc * 8 + k];
            xk[k] = x_s[lane * 65 + kc * 8 + k];
        }
#pragma unroll
        for (int dd = 0; dd < 8; dd++) {
            const int d = wvu * 8 + dd;            // wave-uniform -> s_loads
            const float* wlr = wl    + d * 64 + kc * 8;
            const float* wrr = wr    + d * 64 + kc * 8;
            const float* wsr = wskip + d * 64 + kc * 8;
#pragma unroll
            for (int k = 0; k < 8; k++) {
                acc1[dd] += ak[k] * wlr[k];
                acc2[dd] += hk[k] * wrr[k];
                acc3[dd] += xk[k] * wsr[k];
            }
        }
    }
    __syncthreads();   // all waves done reading agg_s before alias-write

    float* out_s = agg_s;
#pragma unroll
    for (int dd = 0; dd < 8; dd++) {
        const int d = wvu * 8 + dd;
        float z = acc1[dd] * inv + acc2[dd] + bl[d];
        z = (z >= 0.f) ? z : aprelu[d] * z;
        out_s[lane * 65 + d] = z + acc3[dd] + bskip[d];
    }
    __syncthreads();

    for (int i = tid; i < 64 * 64; i += BLOCK) {
        const int nl = i >> 6, d = i & 63;
        const int nd = tileBase + nl;
        if (nd < n) out[(size_t)nd * 64 + d] = out_s[nl * 65 + d];
    }
}

extern "C" void kernel_launch(void* const* d_in, const int* in_sizes, int n_in,
                              void* d_out, int out_size, void* d_ws, size_t ws_size,
                              hipStream_t stream)
{
    const float* x   = (const float*)d_in[0];
    const int*   ei  = (const int*)d_in[1];
    const float* wl0 = (const float*)d_in[2];
    const float* bl0 = (const float*)d_in[3];
    const float* wr0 = (const float*)d_in[4];
    const float* ws0 = (const float*)d_in[5];
    const float* bs0 = (const float*)d_in[6];
    const float* a0  = (const float*)d_in[7];
    const float* wl1 = (const float*)d_in[8];
    const float* bl1 = (const float*)d_in[9];
    const float* wr1 = (const float*)d_in[10];
    const float* ws1 = (const float*)d_in[11];
    const float* bs1 = (const float*)d_in[12];
    const float* a1  = (const float*)d_in[13];

    const int n = in_sizes[0] / 64;
    const int E = in_sizes[1] / 2;
    const int* src = ei;
    const int* dst = ei + E;

    int* deg            = (int*)d_ws;
    int* cursor         = deg + n;
    int* rowStart       = cursor + n;
    int* bsum           = rowStart + n;
    int* bsumX          = bsum + 512;
    unsigned int* esort = (unsigned int*)(bsumX + 512);
    float* h1           = (float*)(esort + E);

    hipMemsetAsync(deg, 0, (size_t)n * sizeof(int), stream);

    const int nb = (n + 255) / 256;   // 391 <= 512

    hist_kernel<<<2048, 256, 0, stream>>>(dst, deg, E);
    bsum_kernel<<<nb, 256, 0, stream>>>(deg, bsum, n);
    scanb_kernel<<<1, 512, 0, stream>>>(bsum, bsumX, nb);
    rowstart_kernel<<<nb, 256, 0, stream>>>(deg, bsumX, rowStart, cursor, n);
    fill_kernel<<<2048, 256, 0, stream>>>(src, dst, cursor, esort, E);

    const int ntiles = (n + 63) / 64;

    layer_kernel<<<ntiles, BLOCK, 0, stream>>>(rowStart, deg, esort,
        x, x, wl0, bl0, wr0, ws0, bs0, a0, h1, n, E);
    layer_kernel<<<ntiles, BLOCK, 0, stream>>>(rowStart, deg, esort,
        h1, x, wl1, bl1, wr1, ws1, bs1, a1, (float*)d_out, n, E);
}